// Round 13
// baseline (742.622 us; speedup 1.0000x reference)
//
#include <hip/hip_runtime.h>
#include <cmath>

#define NS 16384   // samples
#define LS 4096    // memory slots
#define DF 1024    // feature dim
#define SHRINK_T 0.0025f
#define EPS_T 1e-12f

using f16 = _Float16;
using f16x4 = __attribute__((ext_vector_type(4))) _Float16;
using f16x8 = __attribute__((ext_vector_type(8))) _Float16;
using f32x16 = __attribute__((ext_vector_type(16))) float;

#define NSEG 64   // centroid partial segments

// ---------------- K_split: f32 -> f16 hi + f16 lo residual ----------------
__global__ void split_kernel(const float* __restrict__ src,
                             f16* __restrict__ hi, f16* __restrict__ lo, int n4) {
    int i = blockIdx.x * 256 + threadIdx.x;
    if (i >= n4) return;
    float4 v = reinterpret_cast<const float4*>(src)[i];
    f16x4 h, l;
    h[0] = (f16)v.x; h[1] = (f16)v.y; h[2] = (f16)v.z; h[3] = (f16)v.w;
    l[0] = (f16)(v.x - (float)h[0]);
    l[1] = (f16)(v.y - (float)h[1]);
    l[2] = (f16)(v.z - (float)h[2]);
    l[3] = (f16)(v.w - (float)h[3]);
    reinterpret_cast<f16x4*>(hi)[i] = h;
    reinterpret_cast<f16x4*>(lo)[i] = l;
}

// ---------------- K0: centroid, two-stage deterministic ----------------
__global__ void centroid_part_kernel(const float* __restrict__ w, float* __restrict__ part) {
    const int c = blockIdx.x * 256 + threadIdx.x;
    const int seg = blockIdx.y;
    const int l0 = seg * (LS / NSEG);
    float acc = 0.f;
    for (int l = 0; l < LS / NSEG; ++l)
        acc += w[(size_t)(l0 + l) * DF + c];
    part[(size_t)seg * DF + c] = acc;
}

__global__ void centroid_sum_kernel(const float* __restrict__ part, float* __restrict__ cen) {
    const int c = blockIdx.x * 256 + threadIdx.x;
    float acc = 0.f;
    for (int s = 0; s < NSEG; ++s) acc += part[(size_t)s * DF + c];
    cen[c] = acc * (1.0f / (float)LS);
}

// ---------------- K1: S = x @ w^T, 3-term f16-split, 32x32x16 MFMA ----------------
// 256x256 tile, 512 threads = 8 waves (2M x 4N), wave-tile 128x64 (4m x 2n).
// K processed in 64 slices of 16; 4 slice-buffers in LDS (128 KB), pipeline
// depth 3 slices, counted vmcnt(8) (T3/T4), one s_barrier per slice.
// Plane-separated LDS layout [k-half][row][16B]: frag reads hit the LDS
// 1024B/wave floor with zero above-floor bank conflicts (T2 analog).
#define BM 256
#define BN 256
#define NSL (DF / 16)   // 64 k-slices

#define GLOAD16(gptr, lptr)                                                    \
    __builtin_amdgcn_global_load_lds(                                          \
        (const __attribute__((address_space(1))) void*)(gptr),                 \
        (__attribute__((address_space(3))) void*)(lptr), 16, 0, 0)

__global__ __launch_bounds__(512, 2) void gemm_f16_kernel(
    const f16* __restrict__ xh, const f16* __restrict__ xl,
    const f16* __restrict__ wh, const f16* __restrict__ wl,
    float* __restrict__ S, int r0, int rowsChunk)
{
    // [buf][comp: Ah Al Bh Bl][plane(k-half)][row][8 f16] = 128 KB
    __shared__ __align__(16) f16 lds[4][4][2][256][8];

    const int t = threadIdx.x;
    const int lane = t & 63;
    const int wv = t >> 6;                // 0..7
    const int wvm = wv >> 2;              // 0..1 -> row block of 128
    const int wvn = wv & 3;               // 0..3 -> col block of 64
    const int rowBase = r0 + blockIdx.y * BM;
    const int colBase = blockIdx.x * BN;

    f32x16 acc[4][2];
#pragma unroll
    for (int m = 0; m < 4; ++m)
#pragma unroll
        for (int n = 0; n < 2; ++n)
#pragma unroll
            for (int j = 0; j < 16; ++j) acc[m][n][j] = 0.f;

    const int c32 = lane & 31;            // row/col within 32x32 frag
    const int kh = lane >> 5;             // k-half -> plane

    // staging: thread t stages chunk t of each component per slice.
    // chunk t -> plane = t>>8, row = t&255; LDS byte = t*16 (linear).
    const int prow = t & 255;
    const int pplane = t >> 8;
    const size_t asrc = (size_t)(rowBase + prow) * DF + pplane * 8;
    const size_t bsrc = (size_t)(colBase + prow) * DF + pplane * 8;
    const int dstoff = (t & 448) * 8;     // wave-uniform f16 offset ((t&~63)*16 B)

#define STAGE(j)                                                        \
    do {                                                                \
        const int _b = (j) & 3;                                         \
        const int _k = (j) * 16;                                        \
        GLOAD16(xh + asrc + _k, &lds[_b][0][0][0][0] + dstoff);         \
        GLOAD16(xl + asrc + _k, &lds[_b][1][0][0][0] + dstoff);         \
        GLOAD16(wh + bsrc + _k, &lds[_b][2][0][0][0] + dstoff);         \
        GLOAD16(wl + bsrc + _k, &lds[_b][3][0][0][0] + dstoff);         \
    } while (0)

    STAGE(0); STAGE(1); STAGE(2);         // 12 loads in flight

    for (int j = 0; j < NSL; ++j) {
        const int b = j & 3;
        // counted wait: complete slice j's 4 loads; keep j+1,j+2 in flight.
        if (j <= 61)      asm volatile("s_waitcnt vmcnt(8)" ::: "memory");
        else if (j == 62) asm volatile("s_waitcnt vmcnt(4)" ::: "memory");
        else              asm volatile("s_waitcnt vmcnt(0)" ::: "memory");
        __builtin_amdgcn_sched_barrier(0);
        __builtin_amdgcn_s_barrier();     // slice j visible; buf (j+3)&3 free
        __builtin_amdgcn_sched_barrier(0);

        // ---- frag reads: 12 x ds_read_b128, bank-conflict-free planes ----
        f16x8 amh[4], aml[4], bnh[2], bnl[2];
#pragma unroll
        for (int m = 0; m < 4; ++m) {
            const int r = wvm * 128 + m * 32 + c32;
            amh[m] = *(const f16x8*)&lds[b][0][kh][r][0];
            aml[m] = *(const f16x8*)&lds[b][1][kh][r][0];
        }
#pragma unroll
        for (int n = 0; n < 2; ++n) {
            const int r = wvn * 64 + n * 32 + c32;
            bnh[n] = *(const f16x8*)&lds[b][2][kh][r][0];
            bnl[n] = *(const f16x8*)&lds[b][3][kh][r][0];
        }

        if (j <= 60) STAGE(j + 3);        // refill freed buffer; flies under MFMA

        // ---- 24 MFMA (hi*hi + hi*lo + lo*hi) ----
        __builtin_amdgcn_s_setprio(1);
#pragma unroll
        for (int m = 0; m < 4; ++m)
#pragma unroll
            for (int n = 0; n < 2; ++n) {
                acc[m][n] = __builtin_amdgcn_mfma_f32_32x32x16_f16(amh[m], bnh[n], acc[m][n], 0, 0, 0);
                acc[m][n] = __builtin_amdgcn_mfma_f32_32x32x16_f16(amh[m], bnl[n], acc[m][n], 0, 0, 0);
                acc[m][n] = __builtin_amdgcn_mfma_f32_32x32x16_f16(aml[m], bnh[n], acc[m][n], 0, 0, 0);
            }
        __builtin_amdgcn_s_setprio(0);
    }
#undef STAGE

    // C write: col = lane&31, row = (reg&3) + 8*(reg>>2) + 4*(lane>>5)  [m74/m101]
#pragma unroll
    for (int m = 0; m < 4; ++m) {
        const int rb = blockIdx.y * BM + wvm * 128 + m * 32 + 4 * kh;  // chunk-local
#pragma unroll
        for (int n = 0; n < 2; ++n) {
            const int cc = colBase + wvn * 64 + n * 32 + c32;
#pragma unroll
            for (int reg = 0; reg < 16; ++reg) {
                const int rr = rb + (reg & 3) + 8 * (reg >> 2);
                if (rr < rowsChunk)
                    S[(size_t)rr * LS + cc] = acc[m][n][reg];
            }
        }
    }
}

// ---------------- K2: per-row softmax/shrink/norm + all outputs (float4) ----------------
__global__ __launch_bounds__(256) void pass2_kernel(
    const float* __restrict__ S, const float* __restrict__ x,
    const float* __restrict__ w, const float* __restrict__ cen,
    float* __restrict__ out, int r0)
{
    constexpr int T = 256;
    __shared__ __align__(16) float att_lds[LS];
    __shared__ float red[T];
    __shared__ int redi[T];

    const int t = threadIdx.x;
    const size_t row = (size_t)r0 + blockIdx.x;
    const float4* s4 = (const float4*)(S + (size_t)blockIdx.x * (size_t)LS);

    float* const out_output = out;
    float* const out_att  = out + (size_t)NS * DF;
    float* const out_nl   = out + (size_t)NS * DF + (size_t)NS * LS;
    float* const out_nl2  = out + (size_t)2 * NS * DF + (size_t)NS * LS;
    float* const out_mask = out + (size_t)3 * NS * DF + (size_t)NS * LS;

    float sv[16];
    float mx = -INFINITY;
#pragma unroll
    for (int i = 0; i < 4; ++i) {
        float4 v = s4[i * 256 + t];
        sv[i * 4 + 0] = v.x; sv[i * 4 + 1] = v.y;
        sv[i * 4 + 2] = v.z; sv[i * 4 + 3] = v.w;
        mx = fmaxf(mx, fmaxf(fmaxf(v.x, v.y), fmaxf(v.z, v.w)));
    }
    red[t] = mx;
    __syncthreads();
    for (int off = 128; off >= 1; off >>= 1) {
        if (t < off) red[t] = fmaxf(red[t], red[t + off]);
        __syncthreads();
    }
    const float m = red[0];
    __syncthreads();

    float zs = 0.f;
#pragma unroll
    for (int i = 0; i < 16; ++i) {
        sv[i] = expf(sv[i] - m);
        zs += sv[i];
    }
    red[t] = zs;
    __syncthreads();
    for (int off = 128; off >= 1; off >>= 1) {
        if (t < off) red[t] += red[t + off];
        __syncthreads();
    }
    const float Z = red[0];
    __syncthreads();

    float l1 = 0.f;
#pragma unroll
    for (int i = 0; i < 16; ++i) {
        float a = sv[i] / Z;
        float r = a - SHRINK_T;
        float v = (r > 0.f) ? (r * a) / (r + EPS_T) : 0.f;
        sv[i] = v;
        l1 += v;
    }
    red[t] = l1;
    __syncthreads();
    for (int off = 128; off >= 1; off >>= 1) {
        if (t < off) red[t] += red[t + off];
        __syncthreads();
    }
    const float nrm = fmaxf(red[0], EPS_T);
    __syncthreads();

    float bv = -INFINITY; int bi = LS;
    float mn = INFINITY;
    float4* const attl4 = (float4*)att_lds;
    float4* const att4o = (float4*)(out_att + row * LS);
#pragma unroll
    for (int i = 0; i < 4; ++i) {
        float4 vn4;
        vn4.x = sv[i * 4 + 0] / nrm; vn4.y = sv[i * 4 + 1] / nrm;
        vn4.z = sv[i * 4 + 2] / nrm; vn4.w = sv[i * 4 + 3] / nrm;
        sv[i * 4 + 0] = vn4.x; sv[i * 4 + 1] = vn4.y;
        sv[i * 4 + 2] = vn4.z; sv[i * 4 + 3] = vn4.w;
        attl4[i * 256 + t] = vn4;
        att4o[i * 256 + t] = vn4;
#pragma unroll
        for (int c = 0; c < 4; ++c) {
            const float v = sv[i * 4 + c];
            const int j = i * 1024 + 4 * t + c;
            if (v > bv) { bv = v; bi = j; }
            mn = fminf(mn, v);
        }
    }
    __syncthreads();

    red[t] = bv; redi[t] = bi;
    __syncthreads();
    for (int off = 128; off >= 1; off >>= 1) {
        if (t < off) {
            float ov = red[t + off]; int oi = redi[t + off];
            if (ov > red[t] || (ov == red[t] && oi < redi[t])) { red[t] = ov; redi[t] = oi; }
        }
        __syncthreads();
    }
    const int ind = redi[0];
    __syncthreads();

    red[t] = mn;
    __syncthreads();
    for (int off = 128; off >= 1; off >>= 1) {
        if (t < off) red[t] = fminf(red[t], red[t + off]);
        __syncthreads();
    }
    const float rowmin = red[0];
    __syncthreads();

    bv = -INFINITY; bi = LS;
#pragma unroll
    for (int i = 0; i < 4; ++i)
#pragma unroll
        for (int c = 0; c < 4; ++c) {
            const int j = i * 1024 + 4 * t + c;
            const float vv = (j == ind) ? rowmin : sv[i * 4 + c];
            if (vv > bv) { bv = vv; bi = j; }
        }
    red[t] = bv; redi[t] = bi;
    __syncthreads();
    for (int off = 128; off >= 1; off >>= 1) {
        if (t < off) {
            float ov = red[t + off]; int oi = redi[t + off];
            if (ov > red[t] || (ov == red[t] && oi < redi[t])) { red[t] = ov; redi[t] = oi; }
        }
        __syncthreads();
    }
    const int ind2 = redi[0];
    __syncthreads();

    const int lane = t & 63;
    float4 oa = {0.f, 0.f, 0.f, 0.f};
    for (int k0 = 0; k0 < LS; k0 += 64) {
        float av = att_lds[k0 + lane];
        unsigned long long msk = __ballot(av > 0.f);
        while (msk) {
            int b = __ffsll((unsigned long long)msk) - 1;
            msk &= msk - 1;
            float vv = att_lds[k0 + b];
            float4 wv4 = ((const float4*)(w + (size_t)(k0 + b) * DF))[t];
            oa.x = fmaf(vv, wv4.x, oa.x);
            oa.y = fmaf(vv, wv4.y, oa.y);
            oa.z = fmaf(vv, wv4.z, oa.z);
            oa.w = fmaf(vv, wv4.w, oa.w);
        }
    }
    ((float4*)(out_output + row * DF))[t] = oa;

    ((float4*)(out_nl  + row * DF))[t] = ((const float4*)(w + (size_t)ind  * DF))[t];
    ((float4*)(out_nl2 + row * DF))[t] = ((const float4*)(w + (size_t)ind2 * DF))[t];

    float4 xv = ((const float4*)(x + row * DF))[t];
    float4 cv = ((const float4*)cen)[t];
    float ds = 0.f;
    ds = fmaf(xv.x - cv.x, xv.x - cv.x, ds);
    ds = fmaf(xv.y - cv.y, xv.y - cv.y, ds);
    ds = fmaf(xv.z - cv.z, xv.z - cv.z, ds);
    ds = fmaf(xv.w - cv.w, xv.w - cv.w, ds);
    red[t] = ds;
    __syncthreads();
    for (int off = 128; off >= 1; off >>= 1) {
        if (t < off) red[t] += red[t + off];
        __syncthreads();
    }
    if (t == 0) {
        float dist = sqrtf(red[0]);
        out_mask[row] = (dist < 1.0f) ? 1.0f : 0.0f;
    }
}

// ---------------- host ----------------
extern "C" void kernel_launch(void* const* d_in, const int* in_sizes, int n_in,
                              void* d_out, int out_size, void* d_ws, size_t ws_size,
                              hipStream_t stream)
{
    const float* x = (const float*)d_in[0];
    const float* w = (const float*)d_in[1];
    float* out = (float*)d_out;

    // workspace layout: cen | partial | xh | xl | wh | wl | S
    float* cen = (float*)d_ws;
    float* part = cen + DF;
    f16* xh = (f16*)(part + (size_t)NSEG * DF);
    f16* xl = xh + (size_t)NS * DF;
    f16* wh = xl + (size_t)NS * DF;
    f16* wl = wh + (size_t)LS * DF;
    float* S = (float*)(wl + (size_t)LS * DF);

    const size_t head_bytes = sizeof(float) * (DF + (size_t)NSEG * DF)
                            + (size_t)2 * 2 * NS * DF + (size_t)2 * 2 * LS * DF;
    long cap_rows = (long)((ws_size - head_bytes) / (sizeof(float) * LS));
    if (cap_rows > NS) cap_rows = NS;
    if (cap_rows < 1) cap_rows = 1;
    int chunk = (cap_rows >= BM) ? (int)(cap_rows - (cap_rows % BM)) : (int)cap_rows;

    centroid_part_kernel<<<dim3(DF / 256, NSEG), 256, 0, stream>>>(w, part);
    centroid_sum_kernel<<<DF / 256, 256, 0, stream>>>(part, cen);
    split_kernel<<<(NS * DF / 4 + 255) / 256, 256, 0, stream>>>(x, xh, xl, NS * DF / 4);
    split_kernel<<<(LS * DF / 4 + 255) / 256, 256, 0, stream>>>(w, wh, wl, LS * DF / 4);

    for (int r0 = 0; r0 < NS; r0 += chunk) {
        int rows = (NS - r0 < chunk) ? (NS - r0) : chunk;
        dim3 grid((LS + BN - 1) / BN, (rows + BM - 1) / BM);
        gemm_f16_kernel<<<grid, 512, 0, stream>>>(xh, xl, wh, wl, S, r0, rows);
        pass2_kernel<<<rows, 256, 0, stream>>>(S, x, w, cen, out, r0);
    }
}

// Round 14
// 729.844 us; speedup vs baseline: 1.0175x; 1.0175x over previous
//
#include <hip/hip_runtime.h>
#include <cmath>

#define NS 16384   // samples
#define LS 4096    // memory slots
#define DF 1024    // feature dim
#define SHRINK_T 0.0025f
#define EPS_T 1e-12f

using f16 = _Float16;
using f16x4 = __attribute__((ext_vector_type(4))) _Float16;
using f16x8 = __attribute__((ext_vector_type(8))) _Float16;
using f32x16 = __attribute__((ext_vector_type(16))) float;

#define NSEG 64   // centroid partial segments

// ---------------- K_split: f32 -> f16 hi + f16 lo residual ----------------
__global__ void split_kernel(const float* __restrict__ src,
                             f16* __restrict__ hi, f16* __restrict__ lo, int n4) {
    int i = blockIdx.x * 256 + threadIdx.x;
    if (i >= n4) return;
    float4 v = reinterpret_cast<const float4*>(src)[i];
    f16x4 h, l;
    h[0] = (f16)v.x; h[1] = (f16)v.y; h[2] = (f16)v.z; h[3] = (f16)v.w;
    l[0] = (f16)(v.x - (float)h[0]);
    l[1] = (f16)(v.y - (float)h[1]);
    l[2] = (f16)(v.z - (float)h[2]);
    l[3] = (f16)(v.w - (float)h[3]);
    reinterpret_cast<f16x4*>(hi)[i] = h;
    reinterpret_cast<f16x4*>(lo)[i] = l;
}

// ---------------- K0: centroid, two-stage deterministic ----------------
__global__ void centroid_part_kernel(const float* __restrict__ w, float* __restrict__ part) {
    const int c = blockIdx.x * 256 + threadIdx.x;
    const int seg = blockIdx.y;
    const int l0 = seg * (LS / NSEG);
    float acc = 0.f;
    for (int l = 0; l < LS / NSEG; ++l)
        acc += w[(size_t)(l0 + l) * DF + c];
    part[(size_t)seg * DF + c] = acc;
}

__global__ void centroid_sum_kernel(const float* __restrict__ part, float* __restrict__ cen) {
    const int c = blockIdx.x * 256 + threadIdx.x;
    float acc = 0.f;
    for (int s = 0; s < NSEG; ++s) acc += part[(size_t)s * DF + c];
    cen[c] = acc * (1.0f / (float)LS);
}

// ---------------- K1: S = x @ w^T, 3-term f16-split, 32x32x16 MFMA ----------------
// r8 champion skeleton (128x128 tile, 4 waves 64x64, BK=32, single 32 KB LDS
// set, 2 barriers/kt, register-fragment prefetch) with ONE change: LDS stored
// plane-separated [kchunk 0..3][row 0..127][8 f16] per component -> fragment
// ds_read_b128 is bank-balanced at the 8-touch floor (r13 proved counter=0).
#define BM 128
#define BN 128
#define BK 32
#define NKT (DF / BK)   // 32

#define GLOAD16(gptr, lptr)                                                    \
    __builtin_amdgcn_global_load_lds(                                          \
        (const __attribute__((address_space(1))) void*)(gptr),                 \
        (__attribute__((address_space(3))) void*)(lptr), 16, 0, 0)

__global__ __launch_bounds__(256) void gemm_f16_kernel(
    const f16* __restrict__ xh, const f16* __restrict__ xl,
    const f16* __restrict__ wh, const f16* __restrict__ wl,
    float* __restrict__ S, int r0, int rowsChunk)
{
    // [kchunk][row][8 f16] per component: 8 KB each, 32 KB total
    __shared__ __align__(16) f16 Ah[4][BM][8];
    __shared__ __align__(16) f16 Al[4][BM][8];
    __shared__ __align__(16) f16 Bh[4][BN][8];
    __shared__ __align__(16) f16 Bl[4][BN][8];

    const int t = threadIdx.x;
    const int lane = t & 63;
    const int wv = t >> 6;                 // wave id 0..3
    const int wr = (wv >> 1) * 64;         // wave row offset in tile
    const int wc = (wv & 1) * 64;          // wave col offset in tile
    const int rowBase = r0 + blockIdx.y * BM;
    const int colBase = blockIdx.x * BN;

    f32x16 acc[2][2];                      // 2x2 frags of 32x32
#pragma unroll
    for (int m = 0; m < 2; ++m)
#pragma unroll
        for (int n = 0; n < 2; ++n)
#pragma unroll
            for (int j = 0; j < 16; ++j) acc[m][n][j] = 0.f;

    const int c32 = lane & 31;             // row/col within a 32x32 frag
    const int kh = lane >> 5;              // k-half (plane parity)

    // ---- staging geometry: chunk-id cid = t (+256 for issue 1) ----
    // cid -> plane = cid>>7 (0..3), row = cid&127; LDS dest = cid*16 B linear;
    // global src row = rowBase + (cid&127), k-chunk offset = (cid>>7)*8.
    // Issue 1 (cid+256): same row, plane+2 -> src offset +16 f16, dest +2048 f16.
    const size_t aoff = (size_t)(rowBase + (t & 127)) * DF + (t >> 7) * 8;
    const size_t boff = (size_t)(colBase + (t & 127)) * DF + (t >> 7) * 8;
    const int d0 = (t & 192) * 8;          // wave-uniform dest base (f16 elems)
    const int d1 = d0 + 2048;              // planes 2..3

#define STAGE(k0)                                             \
    do {                                                      \
        GLOAD16(xh + aoff + (k0),      &Ah[0][0][0] + d0);    \
        GLOAD16(xh + aoff + (k0) + 16, &Ah[0][0][0] + d1);    \
        GLOAD16(xl + aoff + (k0),      &Al[0][0][0] + d0);    \
        GLOAD16(xl + aoff + (k0) + 16, &Al[0][0][0] + d1);    \
        GLOAD16(wh + boff + (k0),      &Bh[0][0][0] + d0);    \
        GLOAD16(wh + boff + (k0) + 16, &Bh[0][0][0] + d1);    \
        GLOAD16(wl + boff + (k0),      &Bl[0][0][0] + d0);    \
        GLOAD16(wl + boff + (k0) + 16, &Bl[0][0][0] + d1);    \
    } while (0)

    STAGE(0);

    for (int kt = 0; kt < NKT; ++kt) {
        // barrier #1: implicit vmcnt(0) — kt's loads were issued a full MFMA
        // phase ago, drain is mostly complete.
        __syncthreads();

        // ---- read all fragments of kt into registers (16 x ds_read_b128,
        //      plane layout: conflict-free at the 8-touch/bank floor) ----
        f16x8 amh[2][2], aml[2][2], bnh[2][2], bnl[2][2];  // [slice][frag]
#pragma unroll
        for (int s = 0; s < 2; ++s) {
            const int pl = 2 * s + kh;     // plane for this slice/half
#pragma unroll
            for (int m = 0; m < 2; ++m) {
                const int r = wr + m * 32 + c32;
                amh[s][m] = *(const f16x8*)&Ah[pl][r][0];
                aml[s][m] = *(const f16x8*)&Al[pl][r][0];
            }
#pragma unroll
            for (int n = 0; n < 2; ++n) {
                const int c = wc + n * 32 + c32;
                bnh[s][n] = *(const f16x8*)&Bh[pl][c][0];
                bnl[s][n] = *(const f16x8*)&Bl[pl][c][0];
            }
        }

        // barrier #2: implicit lgkmcnt(0) — all waves' ds_reads complete; LDS
        // safe to overwrite.
        __syncthreads();
        if (kt + 1 < NKT) STAGE((kt + 1) * BK);   // DMA flies under the MFMAs

        // ---- 24 MFMA on registers ----
#pragma unroll
        for (int s = 0; s < 2; ++s)
#pragma unroll
            for (int m = 0; m < 2; ++m)
#pragma unroll
                for (int n = 0; n < 2; ++n) {
                    acc[m][n] = __builtin_amdgcn_mfma_f32_32x32x16_f16(amh[s][m], bnh[s][n], acc[m][n], 0, 0, 0);
                    acc[m][n] = __builtin_amdgcn_mfma_f32_32x32x16_f16(amh[s][m], bnl[s][n], acc[m][n], 0, 0, 0);
                    acc[m][n] = __builtin_amdgcn_mfma_f32_32x32x16_f16(aml[s][m], bnh[s][n], acc[m][n], 0, 0, 0);
                }
    }
#undef STAGE

    // C write: col = lane&31, row = (reg&3) + 8*(reg>>2) + 4*(lane>>5)  [m74/m101]
#pragma unroll
    for (int m = 0; m < 2; ++m) {
        const int rb = blockIdx.y * BM + wr + m * 32 + 4 * kh;   // chunk-local
#pragma unroll
        for (int n = 0; n < 2; ++n) {
            const int cc = colBase + wc + n * 32 + c32;
#pragma unroll
            for (int reg = 0; reg < 16; ++reg) {
                const int rr = rb + (reg & 3) + 8 * (reg >> 2);
                if (rr < rowsChunk)
                    S[(size_t)rr * LS + cc] = acc[m][n][reg];
            }
        }
    }
}

// ---------------- K2: per-row softmax/shrink/norm + all outputs (float4) ----------------
__global__ __launch_bounds__(256) void pass2_kernel(
    const float* __restrict__ S, const float* __restrict__ x,
    const float* __restrict__ w, const float* __restrict__ cen,
    float* __restrict__ out, int r0)
{
    constexpr int T = 256;
    __shared__ __align__(16) float att_lds[LS];
    __shared__ float red[T];
    __shared__ int redi[T];

    const int t = threadIdx.x;
    const size_t row = (size_t)r0 + blockIdx.x;
    const float4* s4 = (const float4*)(S + (size_t)blockIdx.x * (size_t)LS);

    float* const out_output = out;
    float* const out_att  = out + (size_t)NS * DF;
    float* const out_nl   = out + (size_t)NS * DF + (size_t)NS * LS;
    float* const out_nl2  = out + (size_t)2 * NS * DF + (size_t)NS * LS;
    float* const out_mask = out + (size_t)3 * NS * DF + (size_t)NS * LS;

    float sv[16];
    float mx = -INFINITY;
#pragma unroll
    for (int i = 0; i < 4; ++i) {
        float4 v = s4[i * 256 + t];
        sv[i * 4 + 0] = v.x; sv[i * 4 + 1] = v.y;
        sv[i * 4 + 2] = v.z; sv[i * 4 + 3] = v.w;
        mx = fmaxf(mx, fmaxf(fmaxf(v.x, v.y), fmaxf(v.z, v.w)));
    }
    red[t] = mx;
    __syncthreads();
    for (int off = 128; off >= 1; off >>= 1) {
        if (t < off) red[t] = fmaxf(red[t], red[t + off]);
        __syncthreads();
    }
    const float m = red[0];
    __syncthreads();

    float zs = 0.f;
#pragma unroll
    for (int i = 0; i < 16; ++i) {
        sv[i] = expf(sv[i] - m);
        zs += sv[i];
    }
    red[t] = zs;
    __syncthreads();
    for (int off = 128; off >= 1; off >>= 1) {
        if (t < off) red[t] += red[t + off];
        __syncthreads();
    }
    const float Z = red[0];
    __syncthreads();

    float l1 = 0.f;
#pragma unroll
    for (int i = 0; i < 16; ++i) {
        float a = sv[i] / Z;
        float r = a - SHRINK_T;
        float v = (r > 0.f) ? (r * a) / (r + EPS_T) : 0.f;
        sv[i] = v;
        l1 += v;
    }
    red[t] = l1;
    __syncthreads();
    for (int off = 128; off >= 1; off >>= 1) {
        if (t < off) red[t] += red[t + off];
        __syncthreads();
    }
    const float nrm = fmaxf(red[0], EPS_T);
    __syncthreads();

    float bv = -INFINITY; int bi = LS;
    float mn = INFINITY;
    float4* const attl4 = (float4*)att_lds;
    float4* const att4o = (float4*)(out_att + row * LS);
#pragma unroll
    for (int i = 0; i < 4; ++i) {
        float4 vn4;
        vn4.x = sv[i * 4 + 0] / nrm; vn4.y = sv[i * 4 + 1] / nrm;
        vn4.z = sv[i * 4 + 2] / nrm; vn4.w = sv[i * 4 + 3] / nrm;
        sv[i * 4 + 0] = vn4.x; sv[i * 4 + 1] = vn4.y;
        sv[i * 4 + 2] = vn4.z; sv[i * 4 + 3] = vn4.w;
        attl4[i * 256 + t] = vn4;
        att4o[i * 256 + t] = vn4;
#pragma unroll
        for (int c = 0; c < 4; ++c) {
            const float v = sv[i * 4 + c];
            const int j = i * 1024 + 4 * t + c;
            if (v > bv) { bv = v; bi = j; }
            mn = fminf(mn, v);
        }
    }
    __syncthreads();

    red[t] = bv; redi[t] = bi;
    __syncthreads();
    for (int off = 128; off >= 1; off >>= 1) {
        if (t < off) {
            float ov = red[t + off]; int oi = redi[t + off];
            if (ov > red[t] || (ov == red[t] && oi < redi[t])) { red[t] = ov; redi[t] = oi; }
        }
        __syncthreads();
    }
    const int ind = redi[0];
    __syncthreads();

    red[t] = mn;
    __syncthreads();
    for (int off = 128; off >= 1; off >>= 1) {
        if (t < off) red[t] = fminf(red[t], red[t + off]);
        __syncthreads();
    }
    const float rowmin = red[0];
    __syncthreads();

    bv = -INFINITY; bi = LS;
#pragma unroll
    for (int i = 0; i < 4; ++i)
#pragma unroll
        for (int c = 0; c < 4; ++c) {
            const int j = i * 1024 + 4 * t + c;
            const float vv = (j == ind) ? rowmin : sv[i * 4 + c];
            if (vv > bv) { bv = vv; bi = j; }
        }
    red[t] = bv; redi[t] = bi;
    __syncthreads();
    for (int off = 128; off >= 1; off >>= 1) {
        if (t < off) {
            float ov = red[t + off]; int oi = redi[t + off];
            if (ov > red[t] || (ov == red[t] && oi < redi[t])) { red[t] = ov; redi[t] = oi; }
        }
        __syncthreads();
    }
    const int ind2 = redi[0];
    __syncthreads();

    const int lane = t & 63;
    float4 oa = {0.f, 0.f, 0.f, 0.f};
    for (int k0 = 0; k0 < LS; k0 += 64) {
        float av = att_lds[k0 + lane];
        unsigned long long msk = __ballot(av > 0.f);
        while (msk) {
            int b = __ffsll((unsigned long long)msk) - 1;
            msk &= msk - 1;
            float vv = att_lds[k0 + b];
            float4 wv4 = ((const float4*)(w + (size_t)(k0 + b) * DF))[t];
            oa.x = fmaf(vv, wv4.x, oa.x);
            oa.y = fmaf(vv, wv4.y, oa.y);
            oa.z = fmaf(vv, wv4.z, oa.z);
            oa.w = fmaf(vv, wv4.w, oa.w);
        }
    }
    ((float4*)(out_output + row * DF))[t] = oa;

    ((float4*)(out_nl  + row * DF))[t] = ((const float4*)(w + (size_t)ind  * DF))[t];
    ((float4*)(out_nl2 + row * DF))[t] = ((const float4*)(w + (size_t)ind2 * DF))[t];

    float4 xv = ((const float4*)(x + row * DF))[t];
    float4 cv = ((const float4*)cen)[t];
    float ds = 0.f;
    ds = fmaf(xv.x - cv.x, xv.x - cv.x, ds);
    ds = fmaf(xv.y - cv.y, xv.y - cv.y, ds);
    ds = fmaf(xv.z - cv.z, xv.z - cv.z, ds);
    ds = fmaf(xv.w - cv.w, xv.w - cv.w, ds);
    red[t] = ds;
    __syncthreads();
    for (int off = 128; off >= 1; off >>= 1) {
        if (t < off) red[t] += red[t + off];
        __syncthreads();
    }
    if (t == 0) {
        float dist = sqrtf(red[0]);
        out_mask[row] = (dist < 1.0f) ? 1.0f : 0.0f;
    }
}

// ---------------- host ----------------
extern "C" void kernel_launch(void* const* d_in, const int* in_sizes, int n_in,
                              void* d_out, int out_size, void* d_ws, size_t ws_size,
                              hipStream_t stream)
{
    const float* x = (const float*)d_in[0];
    const float* w = (const float*)d_in[1];
    float* out = (float*)d_out;

    // workspace layout: cen | partial | xh | xl | wh | wl | S
    float* cen = (float*)d_ws;
    float* part = cen + DF;
    f16* xh = (f16*)(part + (size_t)NSEG * DF);
    f16* xl = xh + (size_t)NS * DF;
    f16* wh = xl + (size_t)NS * DF;
    f16* wl = wh + (size_t)LS * DF;
    float* S = (float*)(wl + (size_t)LS * DF);

    const size_t head_bytes = sizeof(float) * (DF + (size_t)NSEG * DF)
                            + (size_t)2 * 2 * NS * DF + (size_t)2 * 2 * LS * DF;
    long cap_rows = (long)((ws_size - head_bytes) / (sizeof(float) * LS));
    if (cap_rows > NS) cap_rows = NS;
    if (cap_rows < 1) cap_rows = 1;
    int chunk = (cap_rows >= BM) ? (int)(cap_rows - (cap_rows % BM)) : (int)cap_rows;

    centroid_part_kernel<<<dim3(DF / 256, NSEG), 256, 0, stream>>>(w, part);
    centroid_sum_kernel<<<DF / 256, 256, 0, stream>>>(part, cen);
    split_kernel<<<(NS * DF / 4 + 255) / 256, 256, 0, stream>>>(x, xh, xl, NS * DF / 4);
    split_kernel<<<(LS * DF / 4 + 255) / 256, 256, 0, stream>>>(w, wh, wl, LS * DF / 4);

    for (int r0 = 0; r0 < NS; r0 += chunk) {
        int rows = (NS - r0 < chunk) ? (NS - r0) : chunk;
        dim3 grid((LS + BN - 1) / BN, (rows + BM - 1) / BM);
        gemm_f16_kernel<<<grid, 256, 0, stream>>>(xh, xl, wh, wl, S, r0, rows);
        pass2_kernel<<<rows, 256, 0, stream>>>(S, x, w, cen, out, r0);
    }
}